// Round 1
// baseline (104.895 us; speedup 1.0000x reference)
//
#include <hip/hip_runtime.h>
#include <math.h>

#define NPMT 32
#define SINK_EPS 0.05f
#define SINK_INV_EPS 20.0f
#define SINK_ITERS 50
#define NCHUNK 32   // blocks per segment in the reduction kernel

// ---------------------------------------------------------------------------
// Kernel 1: pe_batch[b,p] = sum_{v in seg b} pred[v,p] * mean(charge[v,:])
// Grid: B*NCHUNK blocks x 256 threads. Each block: one contiguous voxel chunk
// of one segment. Wave layout: lane = (voxel_sub<<3)|q4, q4 = float4 column
// (pmts 4*q4..4*q4+3) -> each wave iteration reads 8 voxel rows = 1KB coalesced.
// ---------------------------------------------------------------------------
__global__ __launch_bounds__(256) void segreduce_kernel(
    const float* __restrict__ pred, const float* __restrict__ charge,
    const int* __restrict__ batchstart, const int* __restrict__ batchend,
    float* __restrict__ pe_out)
{
    const int seg   = blockIdx.x / NCHUNK;
    const int chunk = blockIdx.x % NCHUNK;
    const int start = batchstart[seg];
    const int end   = batchend[seg];
    const int len   = end - start;
    const int csize = (len + NCHUNK - 1) / NCHUNK;
    const int cstart = start + chunk * csize;
    const int cend   = min(end, cstart + csize);

    const int tid  = threadIdx.x;
    const int wave = tid >> 6;
    const int lane = tid & 63;
    const int sub  = lane >> 3;   // voxel index within the 8-voxel group
    const int q4   = lane & 7;    // float4 column within the 32-pmt row

    const float4* __restrict__ pred4 = (const float4*)pred;

    float4 acc = make_float4(0.f, 0.f, 0.f, 0.f);

    for (int v0 = cstart + wave * 8; v0 < cend; v0 += 32) {
        const int v = v0 + sub;
        if (v < cend) {
            const float* c = charge + (size_t)v * 3;
            const float q = (c[0] + c[1] + c[2]) * (1.0f / 3.0f);
            const float4 p = pred4[(size_t)v * 8 + q4];
            acc.x = fmaf(p.x, q, acc.x);
            acc.y = fmaf(p.y, q, acc.y);
            acc.z = fmaf(p.z, q, acc.z);
            acc.w = fmaf(p.w, q, acc.w);
        }
    }

    // butterfly over the 8 lanes sharing q4 (masks 8,16,32)
    #pragma unroll
    for (int m = 8; m <= 32; m <<= 1) {
        acc.x += __shfl_xor(acc.x, m);
        acc.y += __shfl_xor(acc.y, m);
        acc.z += __shfl_xor(acc.z, m);
        acc.w += __shfl_xor(acc.w, m);
    }

    __shared__ float lds[4][NPMT];
    if (lane < 8) {
        lds[wave][q4 * 4 + 0] = acc.x;
        lds[wave][q4 * 4 + 1] = acc.y;
        lds[wave][q4 * 4 + 2] = acc.z;
        lds[wave][q4 * 4 + 3] = acc.w;
    }
    __syncthreads();
    if (tid < NPMT) {
        const float s = lds[0][tid] + lds[1][tid] + lds[2][tid] + lds[3][tid];
        atomicAdd(&pe_out[seg * NPMT + tid], s);
    }
}

// ---------------------------------------------------------------------------
// Kernel 2: per-event debiased Sinkhorn divergence + Poisson NLL, accumulated
// into the scalar output. Grid: B*3 blocks x 64 threads (one wave per OT).
// which==0: OT(a,b) weight +1 (+ Poisson term); 1: OT(a,a) -0.5; 2: OT(b,b) -0.5
// ---------------------------------------------------------------------------
__global__ __launch_bounds__(64) void sinkhorn_kernel(
    const float* __restrict__ pe_batch, const float* __restrict__ target_pe,
    const float* __restrict__ pmtpos, float* __restrict__ out, int B)
{
    const int e     = blockIdx.x / 3;
    const int which = blockIdx.x % 3;
    const int lane  = threadIdx.x;     // 0..63
    const int i     = lane & 31;
    const int half  = lane >> 5;
    const int jbase = half * 16;

    __shared__ float C[NPMT][NPMT + 1];   // stride 33: conflict-free both ways
    __shared__ float la[NPMT], lb[NPMT];
    __shared__ float av[NPMT], bv[NPMT];
    __shared__ float fv[NPMT], gv[NPMT];

    // build cost matrix (64 threads x 16 entries)
    #pragma unroll
    for (int t = 0; t < 16; ++t) {
        const int idx = lane * 16 + t;
        const int ci = idx >> 5, cj = idx & 31;
        const float dz = pmtpos[2 * ci]     - pmtpos[2 * cj];
        const float dy = pmtpos[2 * ci + 1] - pmtpos[2 * cj + 1];
        C[ci][cj] = sqrtf(dz * dz + dy * dy + 1e-12f);
    }

    // normalized pdfs for this event
    float pe = 0.f, tg = 0.f;
    if (half == 0) {
        pe = pe_batch[e * NPMT + i];
        tg = target_pe[e * NPMT + i];
    }
    float pes = pe, tgs = tg;
    #pragma unroll
    for (int m = 1; m <= 32; m <<= 1) {
        pes += __shfl_xor(pes, m);
        tgs += __shfl_xor(tgs, m);
    }
    if (half == 0) {
        const float a_ = pe / pes;
        const float b_ = tg / tgs;
        av[i] = a_;
        bv[i] = b_;
        la[i] = __logf(a_ + 1e-30f);
        lb[i] = __logf(b_ + 1e-30f);
        fv[i] = 0.f;
        gv[i] = 0.f;
    }
    __syncthreads();

    // alpha = (which==2) ? b : a ; beta = (which==1) ? a : b
    const float* __restrict__ AL  = (which == 2) ? bv : av;
    const float* __restrict__ LA  = (which == 2) ? lb : la;
    const float* __restrict__ BE  = (which == 1) ? av : bv;
    const float* __restrict__ LB  = (which == 1) ? la : lb;

    for (int it = 0; it < SINK_ITERS; ++it) {
        // f_i = -eps * logsumexp_j( log_b[j] + (g[j] - C[i][j]) / eps )
        float x[16];
        float mx = -1e30f;
        #pragma unroll
        for (int jj = 0; jj < 16; ++jj) {
            const int j = jbase + jj;
            const float v = LB[j] + (gv[j] - C[i][j]) * SINK_INV_EPS;
            x[jj] = v;
            mx = fmaxf(mx, v);
        }
        mx = fmaxf(mx, __shfl_xor(mx, 32));
        float s = 0.f;
        #pragma unroll
        for (int jj = 0; jj < 16; ++jj) s += __expf(x[jj] - mx);
        s += __shfl_xor(s, 32);
        const float fnew = -SINK_EPS * (mx + __logf(s));
        __syncthreads();
        if (half == 0) fv[i] = fnew;
        __syncthreads();

        // g_j = -eps * logsumexp_i( log_a[i] + (f[i] - C[i][j]) / eps )
        float y[16];
        float mg = -1e30f;
        #pragma unroll
        for (int ii = 0; ii < 16; ++ii) {
            const int ir = jbase + ii;
            const float v = LA[ir] + (fv[ir] - C[ir][i]) * SINK_INV_EPS;
            y[ii] = v;
            mg = fmaxf(mg, v);
        }
        mg = fmaxf(mg, __shfl_xor(mg, 32));
        float s2 = 0.f;
        #pragma unroll
        for (int ii = 0; ii < 16; ++ii) s2 += __expf(y[ii] - mg);
        s2 += __shfl_xor(s2, 32);
        const float gnew = -SINK_EPS * (mg + __logf(s2));
        __syncthreads();
        if (half == 0) gv[i] = gnew;
        __syncthreads();
    }

    // OT cost = <alpha, f> + <beta, g>  (alpha = exp(log(a+1e-30)) = a+1e-30)
    float contrib = 0.f;
    if (half == 0)
        contrib = (AL[i] + 1e-30f) * fv[i] + (BE[i] + 1e-30f) * gv[i];
    #pragma unroll
    for (int m = 1; m <= 32; m <<= 1) contrib += __shfl_xor(contrib, m);

    const float w = (which == 0) ? 1.0f : -0.5f;
    if (lane == 0) atomicAdd(out, w * contrib / (float)B);

    // Poisson NLL term (once per event, on the which==0 block)
    if (which == 0) {
        float pterm = 0.f;
        if (half == 0) pterm = pe - tg * __logf(pe + 1e-8f);
        #pragma unroll
        for (int m = 1; m <= 32; m <<= 1) pterm += __shfl_xor(pterm, m);
        if (lane == 0) atomicAdd(out, pterm / (float)(B * NPMT));
    }
}

extern "C" void kernel_launch(void* const* d_in, const int* in_sizes, int n_in,
                              void* d_out, int out_size, void* d_ws, size_t ws_size,
                              hipStream_t stream) {
    const float* pred    = (const float*)d_in[0];
    const float* charge  = (const float*)d_in[1];
    const float* target  = (const float*)d_in[2];
    const int*   bstart  = (const int*)d_in[3];
    const int*   bend    = (const int*)d_in[4];
    const float* pmtpos  = (const float*)d_in[5];
    const int B = in_sizes[3];

    float* pe_batch = (float*)d_ws;       // B*NPMT floats
    float* out = (float*)d_out;

    hipMemsetAsync(pe_batch, 0, (size_t)B * NPMT * sizeof(float), stream);
    hipMemsetAsync(out, 0, sizeof(float), stream);

    segreduce_kernel<<<B * NCHUNK, 256, 0, stream>>>(pred, charge, bstart, bend, pe_batch);
    sinkhorn_kernel<<<B * 3, 64, 0, stream>>>(pe_batch, target, pmtpos, out, B);
}

// Round 2
// 91.627 us; speedup vs baseline: 1.1448x; 1.1448x over previous
//
#include <hip/hip_runtime.h>
#include <math.h>

#define NPMT 32
#define SINK_EPS 0.05f
#define SINK_INV_EPS 20.0f
#define SINK_ITERS 50
#define NCHUNK 32   // blocks per segment in the reduction kernel

// ---------------------------------------------------------------------------
// Kernel 1: partial[seg*NCHUNK+chunk][p] = sum_{v in chunk} pred[v,p]*mean(charge[v])
// Grid: B*NCHUNK blocks x 256 threads. Wave layout: lane = (voxel_sub<<3)|q4,
// q4 = float4 column -> each wave iteration reads 8 voxel rows = 1KB coalesced.
// No atomics, no zero-init: every partial slot is written exactly once.
// ---------------------------------------------------------------------------
__global__ __launch_bounds__(256) void segreduce_kernel(
    const float* __restrict__ pred, const float* __restrict__ charge,
    const int* __restrict__ batchstart, const int* __restrict__ batchend,
    float* __restrict__ partial)
{
    const int seg   = blockIdx.x / NCHUNK;
    const int chunk = blockIdx.x % NCHUNK;
    const int start = batchstart[seg];
    const int end   = batchend[seg];
    const int csize = (end - start + NCHUNK - 1) / NCHUNK;
    const int cstart = start + chunk * csize;
    const int cend   = min(end, cstart + csize);

    const int tid  = threadIdx.x;
    const int wave = tid >> 6;
    const int lane = tid & 63;
    const int sub  = lane >> 3;   // voxel index within the 8-voxel group
    const int q4   = lane & 7;    // float4 column within the 32-pmt row

    const float4* __restrict__ pred4 = (const float4*)pred;

    float4 acc0 = make_float4(0.f, 0.f, 0.f, 0.f);
    float4 acc1 = make_float4(0.f, 0.f, 0.f, 0.f);

    int v = cstart + wave * 8 + sub;
    // unrolled x2: two independent load+fma streams per wave
    for (; v + 32 < cend; v += 64) {
        {
            const float* c = charge + (size_t)v * 3;
            const float q = (c[0] + c[1] + c[2]) * (1.0f / 3.0f);
            const float4 p = pred4[(size_t)v * 8 + q4];
            acc0.x = fmaf(p.x, q, acc0.x);
            acc0.y = fmaf(p.y, q, acc0.y);
            acc0.z = fmaf(p.z, q, acc0.z);
            acc0.w = fmaf(p.w, q, acc0.w);
        }
        {
            const int v2 = v + 32;
            const float* c = charge + (size_t)v2 * 3;
            const float q = (c[0] + c[1] + c[2]) * (1.0f / 3.0f);
            const float4 p = pred4[(size_t)v2 * 8 + q4];
            acc1.x = fmaf(p.x, q, acc1.x);
            acc1.y = fmaf(p.y, q, acc1.y);
            acc1.z = fmaf(p.z, q, acc1.z);
            acc1.w = fmaf(p.w, q, acc1.w);
        }
    }
    for (; v < cend; v += 32) {   // per-lane exit mask handles the ragged tail
        const float* c = charge + (size_t)v * 3;
        const float q = (c[0] + c[1] + c[2]) * (1.0f / 3.0f);
        const float4 p = pred4[(size_t)v * 8 + q4];
        acc0.x = fmaf(p.x, q, acc0.x);
        acc0.y = fmaf(p.y, q, acc0.y);
        acc0.z = fmaf(p.z, q, acc0.z);
        acc0.w = fmaf(p.w, q, acc0.w);
    }
    acc0.x += acc1.x; acc0.y += acc1.y; acc0.z += acc1.z; acc0.w += acc1.w;

    // butterfly over the 8 lanes sharing q4 (masks 8,16,32)
    #pragma unroll
    for (int m = 8; m <= 32; m <<= 1) {
        acc0.x += __shfl_xor(acc0.x, m);
        acc0.y += __shfl_xor(acc0.y, m);
        acc0.z += __shfl_xor(acc0.z, m);
        acc0.w += __shfl_xor(acc0.w, m);
    }

    __shared__ float lds[4][NPMT];
    if (lane < 8) {
        lds[wave][q4 * 4 + 0] = acc0.x;
        lds[wave][q4 * 4 + 1] = acc0.y;
        lds[wave][q4 * 4 + 2] = acc0.z;
        lds[wave][q4 * 4 + 3] = acc0.w;
    }
    __syncthreads();
    if (tid < NPMT) {
        partial[(size_t)blockIdx.x * NPMT + tid] =
            lds[0][tid] + lds[1][tid] + lds[2][tid] + lds[3][tid];
    }
}

// pairwise trees to shorten the dependent chain (no fast-math reassociation)
__device__ __forceinline__ float max16(const float* x) {
    float a = fmaxf(fmaxf(x[0], x[1]), fmaxf(x[2], x[3]));
    float b = fmaxf(fmaxf(x[4], x[5]), fmaxf(x[6], x[7]));
    float c = fmaxf(fmaxf(x[8], x[9]), fmaxf(x[10], x[11]));
    float d = fmaxf(fmaxf(x[12], x[13]), fmaxf(x[14], x[15]));
    return fmaxf(fmaxf(a, b), fmaxf(c, d));
}
__device__ __forceinline__ float expsum16(const float* x, float mx) {
    float e0 = __expf(x[0] - mx), e1 = __expf(x[1] - mx);
    float e2 = __expf(x[2] - mx), e3 = __expf(x[3] - mx);
    float e4 = __expf(x[4] - mx), e5 = __expf(x[5] - mx);
    float e6 = __expf(x[6] - mx), e7 = __expf(x[7] - mx);
    float e8 = __expf(x[8] - mx), e9 = __expf(x[9] - mx);
    float e10 = __expf(x[10] - mx), e11 = __expf(x[11] - mx);
    float e12 = __expf(x[12] - mx), e13 = __expf(x[13] - mx);
    float e14 = __expf(x[14] - mx), e15 = __expf(x[15] - mx);
    float a = (e0 + e1) + (e2 + e3);
    float b = (e4 + e5) + (e6 + e7);
    float c = (e8 + e9) + (e10 + e11);
    float d = (e12 + e13) + (e14 + e15);
    return (a + b) + (c + d);
}

// ---------------------------------------------------------------------------
// Kernel 2: per-event debiased Sinkhorn divergence + Poisson NLL.
// Grid: B*3 blocks x 64 threads (one wave per OT).
// which==0: OT(a,b) +1 (+ Poisson); 1: OT(a,a) -0.5; 2: OT(b,b) -0.5
// ---------------------------------------------------------------------------
__global__ __launch_bounds__(64) void sinkhorn_kernel(
    const float* __restrict__ partial, const float* __restrict__ target_pe,
    const float* __restrict__ pmtpos, float* __restrict__ out, int B)
{
    const int e     = blockIdx.x / 3;
    const int which = blockIdx.x % 3;
    const int lane  = threadIdx.x;     // 0..63
    const int i     = lane & 31;
    const int half  = lane >> 5;
    const int jbase = half * 16;

    __shared__ float C[NPMT][NPMT + 1];   // stride 33: conflict-free both ways
    __shared__ float la[NPMT], lb[NPMT];
    __shared__ float av[NPMT], bv[NPMT];
    __shared__ alignas(16) float fv[NPMT];
    __shared__ alignas(16) float gv[NPMT];

    // build cost matrix (64 threads x 16 entries)
    #pragma unroll
    for (int t = 0; t < 16; ++t) {
        const int idx = lane * 16 + t;
        const int ci = idx >> 5, cj = idx & 31;
        const float dz = pmtpos[2 * ci]     - pmtpos[2 * cj];
        const float dy = pmtpos[2 * ci + 1] - pmtpos[2 * cj + 1];
        C[ci][cj] = sqrtf(dz * dz + dy * dy + 1e-12f);
    }

    // pe[i] from the NCHUNK partials: 16 coalesced 64-float loads + 1 shfl
    const float* part = partial + (size_t)e * NCHUNK * NPMT;
    float pe = 0.f;
    #pragma unroll
    for (int k = 0; k < (NCHUNK * NPMT) / 64; ++k)
        pe += part[k * 64 + lane];
    pe += __shfl_xor(pe, 32);           // both halves now hold pe[i], i=lane&31
    const float tg = target_pe[e * NPMT + i];

    // sums over the 32 pmts (values replicated across halves -> masks 1..16)
    float pes = pe, tgs = tg;
    #pragma unroll
    for (int m = 1; m <= 16; m <<= 1) {
        pes += __shfl_xor(pes, m);
        tgs += __shfl_xor(tgs, m);
    }
    if (half == 0) {
        const float a_ = pe / pes;
        const float b_ = tg / tgs;
        av[i] = a_;
        bv[i] = b_;
        la[i] = __logf(a_ + 1e-30f);
        lb[i] = __logf(b_ + 1e-30f);
        fv[i] = 0.f;
        gv[i] = 0.f;
    }
    __syncthreads();

    // alpha = (which==2) ? b : a ; beta = (which==1) ? a : b
    const float* __restrict__ AL = (which == 2) ? bv : av;
    const float* __restrict__ LA = (which == 2) ? lb : la;
    const float* __restrict__ BE = (which == 1) ? av : bv;
    const float* __restrict__ LB = (which == 1) ? la : lb;

    // iteration-invariant: kb[t] = log_b[j] - C[i][j]/eps ; ka[t] = log_a[r] - C[r][i]/eps
    float kb[16], ka[16];
    #pragma unroll
    for (int t = 0; t < 16; ++t) {
        const int r = jbase + t;
        kb[t] = LB[r] - C[i][r] * SINK_INV_EPS;
        ka[t] = LA[r] - C[r][i] * SINK_INV_EPS;
    }

    const float4* g4 = (const float4*)(gv + jbase);
    const float4* f4 = (const float4*)(fv + jbase);

    for (int it = 0; it < SINK_ITERS; ++it) {
        // f_i = -eps * LSE_j( kb[j] + g[j]/eps )
        float x[16];
        #pragma unroll
        for (int k = 0; k < 4; ++k) {
            const float4 g = g4[k];
            x[4 * k + 0] = fmaf(g.x, SINK_INV_EPS, kb[4 * k + 0]);
            x[4 * k + 1] = fmaf(g.y, SINK_INV_EPS, kb[4 * k + 1]);
            x[4 * k + 2] = fmaf(g.z, SINK_INV_EPS, kb[4 * k + 2]);
            x[4 * k + 3] = fmaf(g.w, SINK_INV_EPS, kb[4 * k + 3]);
        }
        float mx = max16(x);
        mx = fmaxf(mx, __shfl_xor(mx, 32));
        float s = expsum16(x, mx);
        s += __shfl_xor(s, 32);
        const float fnew = -SINK_EPS * (mx + __logf(s));
        if (half == 0) fv[i] = fnew;
        __syncthreads();

        // g_i = -eps * LSE_r( ka[r] + f[r]/eps )
        float y[16];
        #pragma unroll
        for (int k = 0; k < 4; ++k) {
            const float4 f = f4[k];
            y[4 * k + 0] = fmaf(f.x, SINK_INV_EPS, ka[4 * k + 0]);
            y[4 * k + 1] = fmaf(f.y, SINK_INV_EPS, ka[4 * k + 1]);
            y[4 * k + 2] = fmaf(f.z, SINK_INV_EPS, ka[4 * k + 2]);
            y[4 * k + 3] = fmaf(f.w, SINK_INV_EPS, ka[4 * k + 3]);
        }
        float mg = max16(y);
        mg = fmaxf(mg, __shfl_xor(mg, 32));
        float s2 = expsum16(y, mg);
        s2 += __shfl_xor(s2, 32);
        const float gnew = -SINK_EPS * (mg + __logf(s2));
        if (half == 0) gv[i] = gnew;
        __syncthreads();
    }

    // OT cost = <alpha+1e-30, f> + <beta+1e-30, g>
    float contrib = 0.f;
    if (half == 0)
        contrib = (AL[i] + 1e-30f) * fv[i] + (BE[i] + 1e-30f) * gv[i];
    #pragma unroll
    for (int m = 1; m <= 32; m <<= 1) contrib += __shfl_xor(contrib, m);

    const float w = (which == 0) ? 1.0f : -0.5f;
    if (lane == 0) atomicAdd(out, w * contrib / (float)B);

    // Poisson NLL term (once per event)
    if (which == 0) {
        float pterm = 0.f;
        if (half == 0) pterm = pe - tg * __logf(pe + 1e-8f);
        #pragma unroll
        for (int m = 1; m <= 32; m <<= 1) pterm += __shfl_xor(pterm, m);
        if (lane == 0) atomicAdd(out, pterm / (float)(B * NPMT));
    }
}

extern "C" void kernel_launch(void* const* d_in, const int* in_sizes, int n_in,
                              void* d_out, int out_size, void* d_ws, size_t ws_size,
                              hipStream_t stream) {
    const float* pred    = (const float*)d_in[0];
    const float* charge  = (const float*)d_in[1];
    const float* target  = (const float*)d_in[2];
    const int*   bstart  = (const int*)d_in[3];
    const int*   bend    = (const int*)d_in[4];
    const float* pmtpos  = (const float*)d_in[5];
    const int B = in_sizes[3];

    float* partial = (float*)d_ws;      // B*NCHUNK*NPMT floats, all slots written
    float* out = (float*)d_out;

    hipMemsetAsync(out, 0, sizeof(float), stream);
    segreduce_kernel<<<B * NCHUNK, 256, 0, stream>>>(pred, charge, bstart, bend, partial);
    sinkhorn_kernel<<<B * 3, 64, 0, stream>>>(partial, target, pmtpos, out, B);
}